// Round 1
// baseline (844.094 us; speedup 1.0000x reference)
//
#include <hip/hip_runtime.h>
#include <math.h>

#define N_NODES 10000
#define E_EDGES 100000
#define T_TRI   200000
#define NORB    9
#define H_DIM   128
#define C_DIM   64

__device__ __forceinline__ float rl(float v, int k) {
  return __uint_as_float(__builtin_amdgcn_readlane(__float_as_uint(v), k));
}
__device__ __forceinline__ float silu_f(float x) { return x / (1.0f + __expf(-x)); }
__device__ __forceinline__ float sigmoid_f(float x) { return 1.0f / (1.0f + __expf(-x)); }

// K1: h = x @ w_node + b_node ; x1 = h[:, :64]; sigxk = sigmoid(h[:, 64:])
__global__ __launch_bounds__(128) void k_node_mlp(
    const float* __restrict__ x, const float* __restrict__ w_node,
    const float* __restrict__ b_node, float* __restrict__ x1,
    float* __restrict__ sigxk) {
  __shared__ float xs[H_DIM];
  int n = blockIdx.x;
  int c = threadIdx.x;  // 0..127
  xs[c] = x[(size_t)n * H_DIM + c];
  __syncthreads();
  float acc = b_node[c];
#pragma unroll 8
  for (int k = 0; k < H_DIM; ++k)
    acc = fmaf(xs[k], w_node[k * H_DIM + c], acc);
  if (c < C_DIM)
    x1[(size_t)n * C_DIM + c] = acc;
  else
    sigxk[(size_t)n * C_DIM + (c - C_DIM)] = sigmoid_f(acc);
}

// K2: cji2 = silu(silu(cji @ w_c1) @ w_c2), rows = E*NORB, wave per row.
__global__ __launch_bounds__(256, 1) void k_cji_mlp(
    const float* __restrict__ cji, const float* __restrict__ w_c1,
    const float* __restrict__ w_c2, float* __restrict__ cji2, int rows) {
  int lane = threadIdx.x & 63;
  int wid = (blockIdx.x * blockDim.x + threadIdx.x) >> 6;
  int nw = (gridDim.x * blockDim.x) >> 6;
  float w1c[64], w2c[64];
#pragma unroll
  for (int k = 0; k < 64; ++k) w1c[k] = w_c1[k * 64 + lane];
#pragma unroll
  for (int k = 0; k < 64; ++k) w2c[k] = w_c2[k * 64 + lane];
  for (int r = wid; r < rows; r += nw) {
    float v = cji[(size_t)r * 64 + lane];
    float acc = 0.f;
#pragma unroll
    for (int k = 0; k < 64; ++k) acc = fmaf(rl(v, k), w1c[k], acc);
    float t = silu_f(acc);
    acc = 0.f;
#pragma unroll
    for (int k = 0; k < 64; ++k) acc = fmaf(rl(t, k), w2c[k], acc);
    cji2[(size_t)r * 64 + lane] = silu_f(acc);
  }
}

// K3: per-triplet: orb = sum_d (rb_w[kj,d]*shb[t,d]) * cji2[kj,d,:]; normalize;
//     * sigmoid(xk[k]); atomicAdd into agg[edge_idx_ji].
__global__ __launch_bounds__(256, 1) void k_triplet(
    const float* __restrict__ cji2, const float* __restrict__ rb,
    const float* __restrict__ cutoff_w, const float* __restrict__ shb,
    const int* __restrict__ tri_idx_k, const int* __restrict__ edge_idx_kj,
    const int* __restrict__ edge_idx_ji, const float* __restrict__ sigxk,
    float* __restrict__ agg) {
  int lane = threadIdx.x & 63;
  int wid = (blockIdx.x * blockDim.x + threadIdx.x) >> 6;
  int nw = (gridDim.x * blockDim.x) >> 6;
  for (int t = wid; t < T_TRI; t += nw) {
    int e = edge_idx_kj[t];
    float cw = cutoff_w[e];
    const float* crow = cji2 + (size_t)e * (NORB * C_DIM);
    float acc = 0.f;
#pragma unroll
    for (int d = 0; d < NORB; ++d) {
      float coeff = rb[e * NORB + d] * cw * shb[t * NORB + d];
      acc = fmaf(coeff, crow[d * C_DIM + lane], acc);
    }
    float s = acc * acc;
#pragma unroll
    for (int m = 32; m >= 1; m >>= 1) s += __shfl_xor(s, m, 64);
    float scale = 1.0f / fmaxf(sqrtf(s), 1e-12f);
    int kn = tri_idx_k[t];
    float g = sigxk[(size_t)kn * C_DIM + lane];
    float val = acc * scale * g;
    int ej = edge_idx_ji[t];
    atomicAdd(&agg[(size_t)ej * C_DIM + lane], val);
  }
}

// K4: tbw = silu(silu(agg @ w_t1 + b_t1) @ w_t2 + b_t2), rows = E.
__global__ __launch_bounds__(256, 1) void k_tbw_mlp(
    const float* __restrict__ agg, const float* __restrict__ w_t1,
    const float* __restrict__ b_t1, const float* __restrict__ w_t2,
    const float* __restrict__ b_t2, float* __restrict__ tbw) {
  int lane = threadIdx.x & 63;
  int wid = (blockIdx.x * blockDim.x + threadIdx.x) >> 6;
  int nw = (gridDim.x * blockDim.x) >> 6;
  float w1c[64], w2c[64];
#pragma unroll
  for (int k = 0; k < 64; ++k) w1c[k] = w_t1[k * 64 + lane];
#pragma unroll
  for (int k = 0; k < 64; ++k) w2c[k] = w_t2[k * 64 + lane];
  float bt1 = b_t1[lane], bt2 = b_t2[lane];
  for (int r = wid; r < E_EDGES; r += nw) {
    float v = agg[(size_t)r * 64 + lane];
    float acc = bt1;
#pragma unroll
    for (int k = 0; k < 64; ++k) acc = fmaf(rl(v, k), w1c[k], acc);
    float t = silu_f(acc);
    acc = bt2;
#pragma unroll
    for (int k = 0; k < 64; ++k) acc = fmaf(rl(t, k), w2c[k], acc);
    tbw[(size_t)r * 64 + lane] = silu_f(acc);
  }
}

// K5: lcao = normalize( (1+tbw) * sum_d rb_w[e,d]*cji2[e,d,:] ) @ w_basis
__global__ __launch_bounds__(256, 1) void k_lcao(
    const float* __restrict__ cji2, const float* __restrict__ rb,
    const float* __restrict__ cutoff_w, const float* __restrict__ tbw,
    const float* __restrict__ w_basis, float* __restrict__ lcao) {
  int lane = threadIdx.x & 63;
  int wid = (blockIdx.x * blockDim.x + threadIdx.x) >> 6;
  int nw = (gridDim.x * blockDim.x) >> 6;
  float wbc[64];
#pragma unroll
  for (int k = 0; k < 64; ++k) wbc[k] = w_basis[k * 64 + lane];
  for (int e = wid; e < E_EDGES; e += nw) {
    float cw = cutoff_w[e];
    const float* crow = cji2 + (size_t)e * (NORB * C_DIM);
    float acc = 0.f;
#pragma unroll
    for (int d = 0; d < NORB; ++d)
      acc = fmaf(rb[e * NORB + d] * cw, crow[d * C_DIM + lane], acc);
    acc *= (1.0f + tbw[(size_t)e * 64 + lane]);
    float s = acc * acc;
#pragma unroll
    for (int m = 32; m >= 1; m >>= 1) s += __shfl_xor(s, m, 64);
    float scale = 1.0f / fmaxf(sqrtf(s), 1e-12f);
    float nv = acc * scale;
    float o = 0.f;
#pragma unroll
    for (int k = 0; k < 64; ++k) o = fmaf(rl(nv, k), wbc[k], o);
    lcao[(size_t)e * 64 + lane] = o;
  }
}

// K6: fnode = silu(silu([x1_i, x1_j] @ w_n1 + b_n1) @ w_n2 + b_n2);
//     msg = lcao * fnode; atomicAdd into nodeagg[idx_i].
__global__ __launch_bounds__(256, 1) void k_msg(
    const float* __restrict__ x1, const int* __restrict__ idx_i,
    const int* __restrict__ idx_j, const float* __restrict__ w_n1,
    const float* __restrict__ b_n1, const float* __restrict__ w_n2,
    const float* __restrict__ b_n2, const float* __restrict__ lcao,
    float* __restrict__ nodeagg) {
  int lane = threadIdx.x & 63;
  int wid = (blockIdx.x * blockDim.x + threadIdx.x) >> 6;
  int nw = (gridDim.x * blockDim.x) >> 6;
  float wn1a[64], wn1b[64], wn2c[64];
#pragma unroll
  for (int k = 0; k < 64; ++k) wn1a[k] = w_n1[k * 64 + lane];
#pragma unroll
  for (int k = 0; k < 64; ++k) wn1b[k] = w_n1[(64 + k) * 64 + lane];
#pragma unroll
  for (int k = 0; k < 64; ++k) wn2c[k] = w_n2[k * 64 + lane];
  float bn1 = b_n1[lane], bn2 = b_n2[lane];
  for (int e = wid; e < E_EDGES; e += nw) {
    int i = idx_i[e], j = idx_j[e];
    float vi = x1[(size_t)i * 64 + lane];
    float vj = x1[(size_t)j * 64 + lane];
    float acc = bn1;
#pragma unroll
    for (int k = 0; k < 64; ++k) acc = fmaf(rl(vi, k), wn1a[k], acc);
#pragma unroll
    for (int k = 0; k < 64; ++k) acc = fmaf(rl(vj, k), wn1b[k], acc);
    float t = silu_f(acc);
    float acc2 = bn2;
#pragma unroll
    for (int k = 0; k < 64; ++k) acc2 = fmaf(rl(t, k), wn2c[k], acc2);
    float f = silu_f(acc2);
    float m = lcao[(size_t)e * 64 + lane] * f;
    atomicAdd(&nodeagg[(size_t)i * 64 + lane], m);
  }
}

// K7: out = x + nodeagg @ w_out
__global__ __launch_bounds__(256, 1) void k_out(
    const float* __restrict__ x, const float* __restrict__ nodeagg,
    const float* __restrict__ w_out, float* __restrict__ out) {
  int lane = threadIdx.x & 63;
  int wid = (blockIdx.x * blockDim.x + threadIdx.x) >> 6;
  int nw = (gridDim.x * blockDim.x) >> 6;
  float wo0[64], wo1[64];
#pragma unroll
  for (int k = 0; k < 64; ++k) wo0[k] = w_out[k * H_DIM + lane];
#pragma unroll
  for (int k = 0; k < 64; ++k) wo1[k] = w_out[k * H_DIM + 64 + lane];
  for (int n = wid; n < N_NODES; n += nw) {
    float v = nodeagg[(size_t)n * 64 + lane];
    float a0 = 0.f, a1 = 0.f;
#pragma unroll
    for (int k = 0; k < 64; ++k) {
      float a = rl(v, k);
      a0 = fmaf(a, wo0[k], a0);
      a1 = fmaf(a, wo1[k], a1);
    }
    out[(size_t)n * H_DIM + lane] = x[(size_t)n * H_DIM + lane] + a0;
    out[(size_t)n * H_DIM + 64 + lane] = x[(size_t)n * H_DIM + 64 + lane] + a1;
  }
}

extern "C" void kernel_launch(void* const* d_in, const int* in_sizes, int n_in,
                              void* d_out, int out_size, void* d_ws, size_t ws_size,
                              hipStream_t stream) {
  const float* x         = (const float*)d_in[0];
  const float* cji       = (const float*)d_in[1];
  const float* cutoff_w  = (const float*)d_in[2];
  const float* rb        = (const float*)d_in[3];
  const float* shb       = (const float*)d_in[4];
  const int*   idx_i     = (const int*)d_in[5];
  const int*   idx_j     = (const int*)d_in[6];
  const int*   tri_idx_k = (const int*)d_in[7];
  const int*   e_kj      = (const int*)d_in[8];
  const int*   e_ji      = (const int*)d_in[9];
  const float* w_node    = (const float*)d_in[10];
  const float* b_node    = (const float*)d_in[11];
  const float* w_c1      = (const float*)d_in[12];
  const float* w_c2      = (const float*)d_in[13];
  const float* w_t1      = (const float*)d_in[14];
  const float* b_t1      = (const float*)d_in[15];
  const float* w_t2      = (const float*)d_in[16];
  const float* b_t2      = (const float*)d_in[17];
  const float* w_basis   = (const float*)d_in[18];
  const float* w_n1      = (const float*)d_in[19];
  const float* b_n1      = (const float*)d_in[20];
  const float* w_n2      = (const float*)d_in[21];
  const float* b_n2      = (const float*)d_in[22];
  const float* w_out     = (const float*)d_in[23];
  float* out = (float*)d_out;

  float* ws = (float*)d_ws;
  float* x1      = ws;                       // N*64      =   640,000
  float* sigxk   = x1 + 640000;              // N*64      =   640,000
  float* cji2    = sigxk + 640000;           // E*9*64    = 57,600,000
  float* aggbuf  = cji2 + 57600000;          // E*64      =  6,400,000 (reused as lcao)
  float* tbw     = aggbuf + 6400000;         // E*64      =  6,400,000
  float* nodeagg = tbw + 6400000;            // N*64      =    640,000
  float* lcao    = aggbuf;                   // reuse (agg dead after K4)

  hipMemsetAsync(aggbuf, 0, (size_t)6400000 * sizeof(float), stream);
  hipMemsetAsync(nodeagg, 0, (size_t)640000 * sizeof(float), stream);

  k_node_mlp<<<N_NODES, 128, 0, stream>>>(x, w_node, b_node, x1, sigxk);
  k_cji_mlp<<<2048, 256, 0, stream>>>(cji, w_c1, w_c2, cji2, E_EDGES * NORB);
  k_triplet<<<2048, 256, 0, stream>>>(cji2, rb, cutoff_w, shb, tri_idx_k, e_kj,
                                      e_ji, sigxk, aggbuf);
  k_tbw_mlp<<<512, 256, 0, stream>>>(aggbuf, w_t1, b_t1, w_t2, b_t2, tbw);
  k_lcao<<<1024, 256, 0, stream>>>(cji2, rb, cutoff_w, tbw, w_basis, lcao);
  k_msg<<<1024, 256, 0, stream>>>(x1, idx_i, idx_j, w_n1, b_n1, w_n2, b_n2,
                                  lcao, nodeagg);
  k_out<<<256, 256, 0, stream>>>(x, nodeagg, w_out, out);
}

// Round 2
// 343.537 us; speedup vs baseline: 2.4571x; 2.4571x over previous
//
#include <hip/hip_runtime.h>
#include <math.h>

typedef __attribute__((ext_vector_type(8))) short bf16x8;
typedef __attribute__((ext_vector_type(4))) float f32x4;
typedef unsigned int uint32;

#define N_NODES 10000
#define E_EDGES 100000
#define T_TRI   200000
#define NORB    9
#define H_DIM   128
#define C_DIM   64
#define LSTR    66   // padded LDS row stride (floats): breaks bank conflicts

__device__ __forceinline__ short f2b(float f) {          // fp32 -> bf16 RTNE
  uint32 u = __float_as_uint(f);
  u += 0x7FFFu + ((u >> 16) & 1u);
  return (short)(u >> 16);
}
__device__ __forceinline__ float b2f(unsigned short u) {
  return __uint_as_float(((uint32)u) << 16);
}
__device__ __forceinline__ float silu_f(float x) { return x / (1.0f + __expf(-x)); }
__device__ __forceinline__ float sigmoid_f(float x) { return 1.0f / (1.0f + __expf(-x)); }
__device__ __forceinline__ float rl(float v, int k) {
  return __uint_as_float(__builtin_amdgcn_readlane(__float_as_uint(v), k));
}
__device__ __forceinline__ f32x4 mfma16(bf16x8 a, bf16x8 b, f32x4 c) {
  return __builtin_amdgcn_mfma_f32_16x16x32_bf16(a, b, c, 0, 0, 0);
}
#define LDS_FENCE() asm volatile("s_waitcnt lgkmcnt(0)" ::: "memory")

// B-frag for W[K][64] row-major: lane holds W[kt*32+(l>>4)*8+b][ct*16+(l&15)]
__device__ __forceinline__ bf16x8 bfrag_w(const float* W, int kt, int ct, int lane) {
  const float* p = W + (size_t)(kt * 32 + ((lane >> 4) * 8)) * 64 + ct * 16 + (lane & 15);
  bf16x8 r;
#pragma unroll
  for (int b = 0; b < 8; ++b) r[b] = f2b(p[(size_t)b * 64]);
  return r;
}
// A-frag from 8 consecutive fp32 (row=lane&15 chosen by caller)
__device__ __forceinline__ bf16x8 afrag_f32(const float* p) {
  f32x4 v0 = *(const f32x4*)p;
  f32x4 v1 = *(const f32x4*)(p + 4);
  bf16x8 r;
  r[0] = f2b(v0[0]); r[1] = f2b(v0[1]); r[2] = f2b(v0[2]); r[3] = f2b(v0[3]);
  r[4] = f2b(v1[0]); r[5] = f2b(v1[1]); r[6] = f2b(v1[2]); r[7] = f2b(v1[3]);
  return r;
}
// A-frag from LDS fp32 tile [16][LSTR]
__device__ __forceinline__ bf16x8 afrag_lds(const float* lds, int lane, int kt) {
  const float* p = lds + (lane & 15) * LSTR + kt * 32 + ((lane >> 4) * 8);
  bf16x8 r;
#pragma unroll
  for (int b = 0; b < 8; ++b) r[b] = f2b(p[b]);
  return r;
}

// K1: h = x @ w_node + b_node ; x1 = h[:, :64]; sigxk = sigmoid(h[:, 64:])
__global__ __launch_bounds__(128) void k_node_mlp(
    const float* __restrict__ x, const float* __restrict__ w_node,
    const float* __restrict__ b_node, float* __restrict__ x1,
    float* __restrict__ sigxk) {
  __shared__ float xs[H_DIM];
  int n = blockIdx.x;
  int c = threadIdx.x;
  xs[c] = x[(size_t)n * H_DIM + c];
  __syncthreads();
  float acc = b_node[c];
#pragma unroll 8
  for (int k = 0; k < H_DIM; ++k)
    acc = fmaf(xs[k], w_node[k * H_DIM + c], acc);
  if (c < C_DIM)
    x1[(size_t)n * C_DIM + c] = acc;
  else
    sigxk[(size_t)n * C_DIM + (c - C_DIM)] = sigmoid_f(acc);
}

// K2: cji2 = silu(silu(cji @ w_c1) @ w_c2), 900000 rows, bf16 MFMA, bf16 out.
__global__ __launch_bounds__(256, 1) void k_cji_mlp_mfma(
    const float* __restrict__ cji, const float* __restrict__ w_c1,
    const float* __restrict__ w_c2, unsigned short* __restrict__ cji2) {
  __shared__ float lds_all[4][16 * LSTR];
  int lane = threadIdx.x & 63;
  float* lds = lds_all[threadIdx.x >> 6];
  int wid = (blockIdx.x * 256 + (int)threadIdx.x) >> 6;
  int nw = (gridDim.x * 256) >> 6;
  bf16x8 w1f[2][4], w2f[2][4];
#pragma unroll
  for (int kt = 0; kt < 2; ++kt)
#pragma unroll
    for (int ct = 0; ct < 4; ++ct) {
      w1f[kt][ct] = bfrag_w(w_c1, kt, ct, lane);
      w2f[kt][ct] = bfrag_w(w_c2, kt, ct, lane);
    }
  const int nstrips = (E_EDGES * NORB) / 16;  // 56250
  int wrow = (lane >> 4) * 4, wcol = lane & 15;
  f32x4 z = {0.f, 0.f, 0.f, 0.f};
  for (int s = wid; s < nstrips; s += nw) {
    const float* ap = cji + (size_t)(s * 16 + (lane & 15)) * 64 + ((lane >> 4) * 8);
    bf16x8 a0 = afrag_f32(ap), a1 = afrag_f32(ap + 32);
#pragma unroll
    for (int ct = 0; ct < 4; ++ct) {
      f32x4 acc = mfma16(a0, w1f[0][ct], z);
      acc = mfma16(a1, w1f[1][ct], acc);
#pragma unroll
      for (int r = 0; r < 4; ++r)
        lds[(wrow + r) * LSTR + ct * 16 + wcol] = silu_f(acc[r]);
    }
    LDS_FENCE();
    bf16x8 t0 = afrag_lds(lds, lane, 0), t1 = afrag_lds(lds, lane, 1);
#pragma unroll
    for (int ct = 0; ct < 4; ++ct) {
      f32x4 acc = mfma16(t0, w2f[0][ct], z);
      acc = mfma16(t1, w2f[1][ct], acc);
#pragma unroll
      for (int r = 0; r < 4; ++r)
        lds[(wrow + r) * LSTR + ct * 16 + wcol] = silu_f(acc[r]);
    }
    LDS_FENCE();
    int orow = lane & 15, ocol = (lane >> 4) * 16;
    const float* lp = lds + orow * LSTR + ocol;
    uint32 o[8];
#pragma unroll
    for (int j = 0; j < 8; ++j) {
      uint32 lo = (uint32)(unsigned short)f2b(lp[2 * j]);
      uint32 hi = (uint32)(unsigned short)f2b(lp[2 * j + 1]);
      o[j] = lo | (hi << 16);
    }
    uint4* dst = (uint4*)(cji2 + (size_t)(s * 16 + orow) * 64 + ocol);
    dst[0] = make_uint4(o[0], o[1], o[2], o[3]);
    dst[1] = make_uint4(o[4], o[5], o[6], o[7]);
  }
}

// K3: per-triplet gather + normalize + gate + atomic segment-sum (cji2 bf16)
__global__ __launch_bounds__(256, 1) void k_triplet(
    const unsigned short* __restrict__ cji2, const float* __restrict__ rb,
    const float* __restrict__ cutoff_w, const float* __restrict__ shb,
    const int* __restrict__ tri_idx_k, const int* __restrict__ edge_idx_kj,
    const int* __restrict__ edge_idx_ji, const float* __restrict__ sigxk,
    float* __restrict__ agg) {
  int lane = threadIdx.x & 63;
  int wid = (blockIdx.x * 256 + (int)threadIdx.x) >> 6;
  int nw = (gridDim.x * 256) >> 6;
  for (int t = wid; t < T_TRI; t += nw) {
    int e = edge_idx_kj[t];
    float cw = cutoff_w[e];
    const unsigned short* crow = cji2 + (size_t)e * (NORB * C_DIM);
    float acc = 0.f;
#pragma unroll
    for (int d = 0; d < NORB; ++d) {
      float coeff = rb[e * NORB + d] * cw * shb[t * NORB + d];
      acc = fmaf(coeff, b2f(crow[d * C_DIM + lane]), acc);
    }
    float s = acc * acc;
#pragma unroll
    for (int m = 32; m >= 1; m >>= 1) s += __shfl_xor(s, m, 64);
    float scale = 1.0f / fmaxf(sqrtf(s), 1e-12f);
    int kn = tri_idx_k[t];
    float g = sigxk[(size_t)kn * C_DIM + lane];
    float val = acc * scale * g;
    int ej = edge_idx_ji[t];
    atomicAdd(&agg[(size_t)ej * C_DIM + lane], val);
  }
}

// K4: tbw = silu(silu(agg @ w_t1 + b_t1) @ w_t2 + b_t2), MFMA, fp32 out.
__global__ __launch_bounds__(256, 1) void k_tbw_mfma(
    const float* __restrict__ agg, const float* __restrict__ w_t1,
    const float* __restrict__ b_t1, const float* __restrict__ w_t2,
    const float* __restrict__ b_t2, float* __restrict__ tbw) {
  __shared__ float lds_all[4][16 * LSTR];
  int lane = threadIdx.x & 63;
  float* lds = lds_all[threadIdx.x >> 6];
  int wid = (blockIdx.x * 256 + (int)threadIdx.x) >> 6;
  int nw = (gridDim.x * 256) >> 6;
  bf16x8 w1f[2][4], w2f[2][4];
  float bn1[4], bn2[4];
#pragma unroll
  for (int ct = 0; ct < 4; ++ct) {
    bn1[ct] = b_t1[ct * 16 + (lane & 15)];
    bn2[ct] = b_t2[ct * 16 + (lane & 15)];
#pragma unroll
    for (int kt = 0; kt < 2; ++kt) {
      w1f[kt][ct] = bfrag_w(w_t1, kt, ct, lane);
      w2f[kt][ct] = bfrag_w(w_t2, kt, ct, lane);
    }
  }
  const int nstrips = E_EDGES / 16;  // 6250
  int wrow = (lane >> 4) * 4, wcol = lane & 15;
  f32x4 z = {0.f, 0.f, 0.f, 0.f};
  for (int s = wid; s < nstrips; s += nw) {
    const float* ap = agg + (size_t)(s * 16 + (lane & 15)) * 64 + ((lane >> 4) * 8);
    bf16x8 a0 = afrag_f32(ap), a1 = afrag_f32(ap + 32);
#pragma unroll
    for (int ct = 0; ct < 4; ++ct) {
      f32x4 acc = mfma16(a0, w1f[0][ct], z);
      acc = mfma16(a1, w1f[1][ct], acc);
#pragma unroll
      for (int r = 0; r < 4; ++r)
        lds[(wrow + r) * LSTR + ct * 16 + wcol] = silu_f(acc[r] + bn1[ct]);
    }
    LDS_FENCE();
    bf16x8 t0 = afrag_lds(lds, lane, 0), t1 = afrag_lds(lds, lane, 1);
#pragma unroll
    for (int ct = 0; ct < 4; ++ct) {
      f32x4 acc = mfma16(t0, w2f[0][ct], z);
      acc = mfma16(t1, w2f[1][ct], acc);
#pragma unroll
      for (int r = 0; r < 4; ++r)
        lds[(wrow + r) * LSTR + ct * 16 + wcol] = silu_f(acc[r] + bn2[ct]);
    }
    LDS_FENCE();
    int orow = lane & 15, ocol = (lane >> 4) * 16;
#pragma unroll
    for (int j = 0; j < 4; ++j) {
      f32x4 v;
#pragma unroll
      for (int k = 0; k < 4; ++k) v[k] = lds[orow * LSTR + ocol + 4 * j + k];
      *(f32x4*)(tbw + (size_t)(s * 16 + orow) * 64 + ocol + 4 * j) = v;
    }
  }
}

// K5: lcao = normalize((1+tbw) * sum_d rb_w*cji2[:,d,:]) @ w_basis (MFMA)
__global__ __launch_bounds__(256, 1) void k_lcao_mfma(
    const unsigned short* __restrict__ cji2, const float* __restrict__ rb,
    const float* __restrict__ cutoff_w, const float* __restrict__ tbw,
    const float* __restrict__ w_basis, float* __restrict__ lcao) {
  __shared__ float lds_all[4][16 * LSTR];
  int lane = threadIdx.x & 63;
  float* lds = lds_all[threadIdx.x >> 6];
  int wid = (blockIdx.x * 256 + (int)threadIdx.x) >> 6;
  int nw = (gridDim.x * 256) >> 6;
  bf16x8 wbf[2][4];
#pragma unroll
  for (int kt = 0; kt < 2; ++kt)
#pragma unroll
    for (int ct = 0; ct < 4; ++ct) wbf[kt][ct] = bfrag_w(w_basis, kt, ct, lane);
  const int nstrips = E_EDGES / 16;
  f32x4 z = {0.f, 0.f, 0.f, 0.f};
  for (int s = wid; s < nstrips; s += nw) {
    for (int ee = 0; ee < 16; ++ee) {
      int e = s * 16 + ee;
      float cw = cutoff_w[e];
      const unsigned short* crow = cji2 + (size_t)e * (NORB * C_DIM);
      float acc = 0.f;
#pragma unroll
      for (int d = 0; d < NORB; ++d)
        acc = fmaf(rb[e * NORB + d] * cw, b2f(crow[d * C_DIM + lane]), acc);
      acc *= (1.0f + tbw[(size_t)e * 64 + lane]);
      float ss = acc * acc;
#pragma unroll
      for (int m = 32; m >= 1; m >>= 1) ss += __shfl_xor(ss, m, 64);
      float scale = 1.0f / fmaxf(sqrtf(ss), 1e-12f);
      lds[ee * LSTR + lane] = acc * scale;
    }
    LDS_FENCE();
    bf16x8 t0 = afrag_lds(lds, lane, 0), t1 = afrag_lds(lds, lane, 1);
    f32x4 o[4];
#pragma unroll
    for (int ct = 0; ct < 4; ++ct) {
      o[ct] = mfma16(t0, wbf[0][ct], z);
      o[ct] = mfma16(t1, wbf[1][ct], o[ct]);
    }
#pragma unroll
    for (int ct = 0; ct < 4; ++ct)
#pragma unroll
      for (int r = 0; r < 4; ++r)
        lds[((lane >> 4) * 4 + r) * LSTR + ct * 16 + (lane & 15)] = o[ct][r];
    LDS_FENCE();
    int orow = lane & 15, ocol = (lane >> 4) * 16;
#pragma unroll
    for (int j = 0; j < 4; ++j) {
      f32x4 v;
#pragma unroll
      for (int k = 0; k < 4; ++k) v[k] = lds[orow * LSTR + ocol + 4 * j + k];
      *(f32x4*)(lcao + (size_t)(s * 16 + orow) * 64 + ocol + 4 * j) = v;
    }
  }
}

// K6: fnode = silu(silu([x1_i,x1_j] @ w_n1 + b_n1) @ w_n2 + b_n2);
//     msg = lcao * fnode; atomic scatter into nodeagg[idx_i]. MFMA.
__global__ __launch_bounds__(256, 1) void k_msg_mfma(
    const float* __restrict__ x1, const int* __restrict__ idx_i,
    const int* __restrict__ idx_j, const float* __restrict__ w_n1,
    const float* __restrict__ b_n1, const float* __restrict__ w_n2,
    const float* __restrict__ b_n2, const float* __restrict__ lcao,
    float* __restrict__ nodeagg) {
  __shared__ float lds_all[4][16 * LSTR];
  int lane = threadIdx.x & 63;
  float* lds = lds_all[threadIdx.x >> 6];
  int wid = (blockIdx.x * 256 + (int)threadIdx.x) >> 6;
  int nw = (gridDim.x * 256) >> 6;
  bf16x8 wn1f[4][4], wn2f[2][4];
  float bn1[4], bn2[4];
#pragma unroll
  for (int ct = 0; ct < 4; ++ct) {
    bn1[ct] = b_n1[ct * 16 + (lane & 15)];
    bn2[ct] = b_n2[ct * 16 + (lane & 15)];
#pragma unroll
    for (int kt = 0; kt < 4; ++kt) wn1f[kt][ct] = bfrag_w(w_n1, kt, ct, lane);
#pragma unroll
    for (int kt = 0; kt < 2; ++kt) wn2f[kt][ct] = bfrag_w(w_n2, kt, ct, lane);
  }
  const int nstrips = E_EDGES / 16;
  int wrow = (lane >> 4) * 4, wcol = lane & 15;
  f32x4 z = {0.f, 0.f, 0.f, 0.f};
  for (int s = wid; s < nstrips; s += nw) {
    int er = s * 16 + (lane & 15);
    int ii = idx_i[er], jj = idx_j[er];
    const float* pi = x1 + (size_t)ii * 64 + ((lane >> 4) * 8);
    const float* pj = x1 + (size_t)jj * 64 + ((lane >> 4) * 8);
    bf16x8 a0 = afrag_f32(pi), a1 = afrag_f32(pi + 32);
    bf16x8 a2 = afrag_f32(pj), a3 = afrag_f32(pj + 32);
#pragma unroll
    for (int ct = 0; ct < 4; ++ct) {
      f32x4 acc = mfma16(a0, wn1f[0][ct], z);
      acc = mfma16(a1, wn1f[1][ct], acc);
      acc = mfma16(a2, wn1f[2][ct], acc);
      acc = mfma16(a3, wn1f[3][ct], acc);
#pragma unroll
      for (int r = 0; r < 4; ++r)
        lds[(wrow + r) * LSTR + ct * 16 + wcol] = silu_f(acc[r] + bn1[ct]);
    }
    LDS_FENCE();
    bf16x8 t0 = afrag_lds(lds, lane, 0), t1 = afrag_lds(lds, lane, 1);
    f32x4 acc2[4];
#pragma unroll
    for (int ct = 0; ct < 4; ++ct) {
      acc2[ct] = mfma16(t0, wn2f[0][ct], z);
      acc2[ct] = mfma16(t1, wn2f[1][ct], acc2[ct]);
    }
#pragma unroll
    for (int r = 0; r < 4; ++r) {
      int ge = s * 16 + (lane >> 4) * 4 + r;
      int ni = idx_i[ge];
#pragma unroll
      for (int ct = 0; ct < 4; ++ct) {
        float f = silu_f(acc2[ct][r] + bn2[ct]);
        float m = lcao[(size_t)ge * 64 + ct * 16 + (lane & 15)] * f;
        atomicAdd(&nodeagg[(size_t)ni * 64 + ct * 16 + (lane & 15)], m);
      }
    }
  }
}

// K7: out = x + nodeagg @ w_out
__global__ __launch_bounds__(256, 1) void k_out(
    const float* __restrict__ x, const float* __restrict__ nodeagg,
    const float* __restrict__ w_out, float* __restrict__ out) {
  int lane = threadIdx.x & 63;
  int wid = (blockIdx.x * 256 + (int)threadIdx.x) >> 6;
  int nw = (gridDim.x * 256) >> 6;
  float wo0[64], wo1[64];
#pragma unroll
  for (int k = 0; k < 64; ++k) wo0[k] = w_out[k * H_DIM + lane];
#pragma unroll
  for (int k = 0; k < 64; ++k) wo1[k] = w_out[k * H_DIM + 64 + lane];
  for (int n = wid; n < N_NODES; n += nw) {
    float v = nodeagg[(size_t)n * 64 + lane];
    float a0 = 0.f, a1 = 0.f;
#pragma unroll
    for (int k = 0; k < 64; ++k) {
      float a = rl(v, k);
      a0 = fmaf(a, wo0[k], a0);
      a1 = fmaf(a, wo1[k], a1);
    }
    out[(size_t)n * H_DIM + lane] = x[(size_t)n * H_DIM + lane] + a0;
    out[(size_t)n * H_DIM + 64 + lane] = x[(size_t)n * H_DIM + 64 + lane] + a1;
  }
}

extern "C" void kernel_launch(void* const* d_in, const int* in_sizes, int n_in,
                              void* d_out, int out_size, void* d_ws, size_t ws_size,
                              hipStream_t stream) {
  const float* x         = (const float*)d_in[0];
  const float* cji       = (const float*)d_in[1];
  const float* cutoff_w  = (const float*)d_in[2];
  const float* rb        = (const float*)d_in[3];
  const float* shb       = (const float*)d_in[4];
  const int*   idx_i     = (const int*)d_in[5];
  const int*   idx_j     = (const int*)d_in[6];
  const int*   tri_idx_k = (const int*)d_in[7];
  const int*   e_kj      = (const int*)d_in[8];
  const int*   e_ji      = (const int*)d_in[9];
  const float* w_node    = (const float*)d_in[10];
  const float* b_node    = (const float*)d_in[11];
  const float* w_c1      = (const float*)d_in[12];
  const float* w_c2      = (const float*)d_in[13];
  const float* w_t1      = (const float*)d_in[14];
  const float* b_t1      = (const float*)d_in[15];
  const float* w_t2      = (const float*)d_in[16];
  const float* b_t2      = (const float*)d_in[17];
  const float* w_basis   = (const float*)d_in[18];
  const float* w_n1      = (const float*)d_in[19];
  const float* b_n1      = (const float*)d_in[20];
  const float* w_n2      = (const float*)d_in[21];
  const float* b_n2      = (const float*)d_in[22];
  const float* w_out     = (const float*)d_in[23];
  float* out = (float*)d_out;

  float* ws = (float*)d_ws;
  float* x1      = ws;                        // N*64
  float* sigxk   = x1 + 640000;               // N*64
  unsigned short* cji2 = (unsigned short*)(sigxk + 640000);  // E*9*64 bf16
  float* aggbuf  = sigxk + 640000 + 28800000; // E*64 (cji2 = 57.6M ushort = 28.8M floats)
  float* tbw     = aggbuf + 6400000;          // E*64
  float* nodeagg = tbw + 6400000;             // N*64
  float* lcao    = aggbuf;                    // reuse (agg dead after K4)

  hipMemsetAsync(aggbuf, 0, (size_t)6400000 * sizeof(float), stream);
  hipMemsetAsync(nodeagg, 0, (size_t)640000 * sizeof(float), stream);

  k_node_mlp<<<N_NODES, 128, 0, stream>>>(x, w_node, b_node, x1, sigxk);
  k_cji_mlp_mfma<<<2048, 256, 0, stream>>>(cji, w_c1, w_c2, cji2);
  k_triplet<<<2048, 256, 0, stream>>>(cji2, rb, cutoff_w, shb, tri_idx_k, e_kj,
                                      e_ji, sigxk, aggbuf);
  k_tbw_mfma<<<512, 256, 0, stream>>>(aggbuf, w_t1, b_t1, w_t2, b_t2, tbw);
  k_lcao_mfma<<<1024, 256, 0, stream>>>(cji2, rb, cutoff_w, tbw, w_basis, lcao);
  k_msg_mfma<<<1024, 256, 0, stream>>>(x1, idx_i, idx_j, w_n1, b_n1, w_n2, b_n2,
                                       lcao, nodeagg);
  k_out<<<256, 256, 0, stream>>>(x, nodeagg, w_out, out);
}

// Round 3
// 296.578 us; speedup vs baseline: 2.8461x; 1.1583x over previous
//
#include <hip/hip_runtime.h>
#include <math.h>

typedef __attribute__((ext_vector_type(8))) short bf16x8;
typedef __attribute__((ext_vector_type(4))) float f32x4;
typedef __attribute__((ext_vector_type(4))) unsigned int uint32x4;
typedef unsigned int uint32;
typedef unsigned short ushort;

#define N_NODES 10000
#define E_EDGES 100000
#define T_TRI   200000
#define NORB    9
#define H_DIM   128
#define C_DIM   64
#define LSTR    68   // padded LDS row stride (floats): 272B, 16B-aligned, 2-way banks

__device__ __forceinline__ ushort f2b_rtne(float f) {
  uint32 u = __float_as_uint(f);
  u += 0x7FFFu + ((u >> 16) & 1u);
  return (ushort)(u >> 16);
}
__device__ __forceinline__ uint32 rtne2(float a, float b) {  // low=a, high=b
  uint32 ua = __float_as_uint(a), ub = __float_as_uint(b);
  ua += 0x7FFFu + ((ua >> 16) & 1u);
  ub += 0x7FFFu + ((ub >> 16) & 1u);
  return (ua >> 16) | (ub & 0xFFFF0000u);
}
__device__ __forceinline__ uint32 trunc2(float a, float b) {  // low=a, high=b
  return (__float_as_uint(a) >> 16) | (__float_as_uint(b) & 0xFFFF0000u);
}
__device__ __forceinline__ float b2f(ushort u) {
  return __uint_as_float(((uint32)u) << 16);
}
__device__ __forceinline__ float silu_f(float x) {
  return x * __builtin_amdgcn_rcpf(1.0f + __expf(-x));
}
__device__ __forceinline__ float sigmoid_f(float x) {
  return __builtin_amdgcn_rcpf(1.0f + __expf(-x));
}
__device__ __forceinline__ float rl(float v, int k) {
  return __uint_as_float(__builtin_amdgcn_readlane(__float_as_uint(v), k));
}
__device__ __forceinline__ f32x4 mfma16(bf16x8 a, bf16x8 b, f32x4 c) {
  return __builtin_amdgcn_mfma_f32_16x16x32_bf16(a, b, c, 0, 0, 0);
}
#define LDS_FENCE() asm volatile("s_waitcnt lgkmcnt(0)" ::: "memory")

// trunc-pack 8 consecutive f32 (16B-aligned) into a bf16x8 frag
__device__ __forceinline__ bf16x8 pack8(const float* p) {
  f32x4 v0 = *(const f32x4*)p;
  f32x4 v1 = *(const f32x4*)(p + 4);
  uint32x4 u;
  u[0] = trunc2(v0[0], v0[1]);
  u[1] = trunc2(v0[2], v0[3]);
  u[2] = trunc2(v1[0], v1[1]);
  u[3] = trunc2(v1[2], v1[3]);
  return __builtin_bit_cast(bf16x8, u);
}
// B-frag (RTNE, done once at kernel start) for W[K][64] row-major
__device__ __forceinline__ bf16x8 bfrag_w(const float* W, int kt, int ct, int lane) {
  const float* p = W + (size_t)(kt * 32 + ((lane >> 4) * 8)) * 64 + ct * 16 + (lane & 15);
  bf16x8 r;
#pragma unroll
  for (int b = 0; b < 8; ++b) r[b] = (short)f2b_rtne(p[(size_t)b * 64]);
  return r;
}

// K1: h = x @ w_node + b_node ; x1b = bf16(h[:,:64]); sigxkb = bf16(sigmoid(h[:,64:]))
__global__ __launch_bounds__(128) void k_node_mlp(
    const float* __restrict__ x, const float* __restrict__ w_node,
    const float* __restrict__ b_node, ushort* __restrict__ x1b,
    ushort* __restrict__ sigxkb) {
  __shared__ float xs[H_DIM];
  int n = blockIdx.x;
  int c = threadIdx.x;
  xs[c] = x[(size_t)n * H_DIM + c];
  __syncthreads();
  float acc = b_node[c];
#pragma unroll 8
  for (int k = 0; k < H_DIM; ++k)
    acc = fmaf(xs[k], w_node[k * H_DIM + c], acc);
  if (c < C_DIM)
    x1b[(size_t)n * C_DIM + c] = f2b_rtne(acc);
  else
    sigxkb[(size_t)n * C_DIM + (c - C_DIM)] = f2b_rtne(sigmoid_f(acc));
}

// K2: cji2 = silu(silu(cji @ w_c1) @ w_c2), 900000 rows, bf16 MFMA, bf16 out.
__global__ __launch_bounds__(256) void k_cji_mlp_mfma(
    const float* __restrict__ cji, const float* __restrict__ w_c1,
    const float* __restrict__ w_c2, ushort* __restrict__ cji2) {
  __shared__ __align__(16) float lds_all[4][16 * LSTR];
  int lane = threadIdx.x & 63;
  float* lds = lds_all[threadIdx.x >> 6];
  int wid = (blockIdx.x * 256 + (int)threadIdx.x) >> 6;
  int nw = (gridDim.x * 256) >> 6;
  bf16x8 w1f[2][4], w2f[2][4];
#pragma unroll
  for (int kt = 0; kt < 2; ++kt)
#pragma unroll
    for (int ct = 0; ct < 4; ++ct) {
      w1f[kt][ct] = bfrag_w(w_c1, kt, ct, lane);
      w2f[kt][ct] = bfrag_w(w_c2, kt, ct, lane);
    }
  const int nstrips = (E_EDGES * NORB) / 16;  // 56250
  int l15 = lane & 15, g = lane >> 4;
  int wrow = g * 4, wcol = l15;
  f32x4 z = {0.f, 0.f, 0.f, 0.f};
  for (int s = wid; s < nstrips; s += nw) {
    const float* ap = cji + (size_t)(s * 16 + l15) * 64 + g * 8;
    bf16x8 a0 = pack8(ap), a1 = pack8(ap + 32);
#pragma unroll
    for (int ct = 0; ct < 4; ++ct) {
      f32x4 acc = mfma16(a0, w1f[0][ct], z);
      acc = mfma16(a1, w1f[1][ct], acc);
#pragma unroll
      for (int r = 0; r < 4; ++r)
        lds[(wrow + r) * LSTR + ct * 16 + wcol] = silu_f(acc[r]);
    }
    LDS_FENCE();
    bf16x8 t0 = pack8(lds + l15 * LSTR + g * 8);
    bf16x8 t1 = pack8(lds + l15 * LSTR + 32 + g * 8);
#pragma unroll
    for (int ct = 0; ct < 4; ++ct) {
      f32x4 acc = mfma16(t0, w2f[0][ct], z);
      acc = mfma16(t1, w2f[1][ct], acc);
#pragma unroll
      for (int r = 0; r < 4; ++r)
        lds[(wrow + r) * LSTR + ct * 16 + wcol] = silu_f(acc[r]);
    }
    LDS_FENCE();
    const float* lp = lds + l15 * LSTR + g * 16;
    f32x4 v0 = *(const f32x4*)lp;
    f32x4 v1 = *(const f32x4*)(lp + 4);
    f32x4 v2 = *(const f32x4*)(lp + 8);
    f32x4 v3 = *(const f32x4*)(lp + 12);
    uint32x4 o0, o1;
    o0[0] = rtne2(v0[0], v0[1]); o0[1] = rtne2(v0[2], v0[3]);
    o0[2] = rtne2(v1[0], v1[1]); o0[3] = rtne2(v1[2], v1[3]);
    o1[0] = rtne2(v2[0], v2[1]); o1[1] = rtne2(v2[2], v2[3]);
    o1[2] = rtne2(v3[0], v3[1]); o1[3] = rtne2(v3[2], v3[3]);
    uint32x4* dst = (uint32x4*)(cji2 + (size_t)(s * 16 + l15) * 64 + g * 16);
    dst[0] = o0;
    dst[1] = o1;
  }
}

// K3: per-triplet gather + normalize + gate + atomic segment-sum
__global__ __launch_bounds__(256) void k_triplet(
    const ushort* __restrict__ cji2, const float* __restrict__ rb,
    const float* __restrict__ cutoff_w, const float* __restrict__ shb,
    const int* __restrict__ tri_idx_k, const int* __restrict__ edge_idx_kj,
    const int* __restrict__ edge_idx_ji, const ushort* __restrict__ sigxkb,
    float* __restrict__ agg) {
  int lane = threadIdx.x & 63;
  int wid = (blockIdx.x * 256 + (int)threadIdx.x) >> 6;
  int nw = (gridDim.x * 256) >> 6;
  for (int t = wid; t < T_TRI; t += nw) {
    int e = edge_idx_kj[t];
    float cw = cutoff_w[e];
    const ushort* crow = cji2 + (size_t)e * (NORB * C_DIM);
    float acc = 0.f;
#pragma unroll
    for (int d = 0; d < NORB; ++d) {
      float coeff = rb[e * NORB + d] * cw * shb[t * NORB + d];
      acc = fmaf(coeff, b2f(crow[d * C_DIM + lane]), acc);
    }
    float s = acc * acc;
#pragma unroll
    for (int m = 32; m >= 1; m >>= 1) s += __shfl_xor(s, m, 64);
    float scale = __builtin_amdgcn_rsqf(fmaxf(s, 1e-30f));
    int kn = tri_idx_k[t];
    float gxe = b2f(sigxkb[(size_t)kn * C_DIM + lane]);
    float val = acc * scale * gxe;
    int ej = edge_idx_ji[t];
    atomicAdd(&agg[(size_t)ej * C_DIM + lane], val);
  }
}

// K4+K5 fused: tbw = MLP(agg) (kept in LDS); lcao = normalize((1+tbw)*sum_d rb_w*cji2) @ w_basis
__global__ __launch_bounds__(256) void k_tbw_lcao(
    const float* __restrict__ agg, const float* __restrict__ w_t1,
    const float* __restrict__ b_t1, const float* __restrict__ w_t2,
    const float* __restrict__ b_t2, const ushort* __restrict__ cji2,
    const float* __restrict__ rb, const float* __restrict__ cutoff_w,
    const float* __restrict__ w_basis, float* __restrict__ lcao) {
  __shared__ __align__(16) float lds_all[4][16 * LSTR];
  int lane = threadIdx.x & 63;
  float* lds = lds_all[threadIdx.x >> 6];
  int wid = (blockIdx.x * 256 + (int)threadIdx.x) >> 6;
  int nw = (gridDim.x * 256) >> 6;
  bf16x8 wt1[2][4], wt2[2][4], wb[2][4];
  float bt1[4], bt2[4];
  int l15 = lane & 15, g = lane >> 4;
#pragma unroll
  for (int ct = 0; ct < 4; ++ct) {
    bt1[ct] = b_t1[ct * 16 + l15];
    bt2[ct] = b_t2[ct * 16 + l15];
#pragma unroll
    for (int kt = 0; kt < 2; ++kt) {
      wt1[kt][ct] = bfrag_w(w_t1, kt, ct, lane);
      wt2[kt][ct] = bfrag_w(w_t2, kt, ct, lane);
      wb[kt][ct] = bfrag_w(w_basis, kt, ct, lane);
    }
  }
  const int nstrips = E_EDGES / 16;  // 6250
  int wrow = g * 4, wcol = l15;
  f32x4 z = {0.f, 0.f, 0.f, 0.f};
  for (int s = wid; s < nstrips; s += nw) {
    const float* ap = agg + (size_t)(s * 16 + l15) * 64 + g * 8;
    bf16x8 a0 = pack8(ap), a1 = pack8(ap + 32);
#pragma unroll
    for (int ct = 0; ct < 4; ++ct) {
      f32x4 acc = mfma16(a0, wt1[0][ct], z);
      acc = mfma16(a1, wt1[1][ct], acc);
#pragma unroll
      for (int r = 0; r < 4; ++r)
        lds[(wrow + r) * LSTR + ct * 16 + wcol] = silu_f(acc[r] + bt1[ct]);
    }
    LDS_FENCE();
    bf16x8 t0 = pack8(lds + l15 * LSTR + g * 8);
    bf16x8 t1 = pack8(lds + l15 * LSTR + 32 + g * 8);
    LDS_FENCE();
#pragma unroll
    for (int ct = 0; ct < 4; ++ct) {
      f32x4 acc = mfma16(t0, wt2[0][ct], z);
      acc = mfma16(t1, wt2[1][ct], acc);
#pragma unroll
      for (int r = 0; r < 4; ++r)
        lds[(wrow + r) * LSTR + ct * 16 + wcol] = silu_f(acc[r] + bt2[ct]);  // tbw tile
    }
    LDS_FENCE();
    // per-edge orbital contraction, gate by (1+tbw), normalize -> overwrite tile rows
    for (int ee = 0; ee < 16; ++ee) {
      int e = s * 16 + ee;
      float cw = cutoff_w[e];
      const ushort* crow = cji2 + (size_t)e * (NORB * C_DIM);
      float acc = 0.f;
#pragma unroll
      for (int d = 0; d < NORB; ++d)
        acc = fmaf(rb[e * NORB + d] * cw, b2f(crow[d * C_DIM + lane]), acc);
      acc *= (1.0f + lds[ee * LSTR + lane]);
      float ss = acc * acc;
#pragma unroll
      for (int m = 32; m >= 1; m >>= 1) ss += __shfl_xor(ss, m, 64);
      float scale = __builtin_amdgcn_rsqf(fmaxf(ss, 1e-30f));
      lds[ee * LSTR + lane] = acc * scale;
    }
    LDS_FENCE();
    bf16x8 n0 = pack8(lds + l15 * LSTR + g * 8);
    bf16x8 n1 = pack8(lds + l15 * LSTR + 32 + g * 8);
    LDS_FENCE();
    f32x4 o[4];
#pragma unroll
    for (int ct = 0; ct < 4; ++ct) {
      o[ct] = mfma16(n0, wb[0][ct], z);
      o[ct] = mfma16(n1, wb[1][ct], o[ct]);
#pragma unroll
      for (int r = 0; r < 4; ++r)
        lds[(wrow + r) * LSTR + ct * 16 + wcol] = o[ct][r];
    }
    LDS_FENCE();
    const float* lp = lds + l15 * LSTR + g * 16;
    f32x4* dst = (f32x4*)(lcao + (size_t)(s * 16 + l15) * 64 + g * 16);
    dst[0] = *(const f32x4*)lp;
    dst[1] = *(const f32x4*)(lp + 4);
    dst[2] = *(const f32x4*)(lp + 8);
    dst[3] = *(const f32x4*)(lp + 12);
  }
}

// K6: fnode = silu(silu([x1_i,x1_j] @ w_n1 + b_n1) @ w_n2 + b_n2);
//     msg = lcao * fnode; atomic scatter into nodeagg[idx_i].
__global__ __launch_bounds__(256) void k_msg_mfma(
    const ushort* __restrict__ x1b, const int* __restrict__ idx_i,
    const int* __restrict__ idx_j, const float* __restrict__ w_n1,
    const float* __restrict__ b_n1, const float* __restrict__ w_n2,
    const float* __restrict__ b_n2, const float* __restrict__ lcao,
    float* __restrict__ nodeagg) {
  __shared__ __align__(16) float lds_all[4][16 * LSTR];
  int lane = threadIdx.x & 63;
  float* lds = lds_all[threadIdx.x >> 6];
  int wid = (blockIdx.x * 256 + (int)threadIdx.x) >> 6;
  int nw = (gridDim.x * 256) >> 6;
  bf16x8 wn1f[4][4], wn2f[2][4];
  float bn1[4], bn2[4];
  int l15 = lane & 15, g = lane >> 4;
#pragma unroll
  for (int ct = 0; ct < 4; ++ct) {
    bn1[ct] = b_n1[ct * 16 + l15];
    bn2[ct] = b_n2[ct * 16 + l15];
#pragma unroll
    for (int kt = 0; kt < 4; ++kt) wn1f[kt][ct] = bfrag_w(w_n1, kt, ct, lane);
#pragma unroll
    for (int kt = 0; kt < 2; ++kt) wn2f[kt][ct] = bfrag_w(w_n2, kt, ct, lane);
  }
  const int nstrips = E_EDGES / 16;
  int wrow = g * 4, wcol = l15;
  f32x4 z = {0.f, 0.f, 0.f, 0.f};
  for (int s = wid; s < nstrips; s += nw) {
    int er = s * 16 + l15;
    int ii = idx_i[er], jj = idx_j[er];
    const uint32x4* pi = (const uint32x4*)(x1b + (size_t)ii * 64 + g * 8);
    const uint32x4* pj = (const uint32x4*)(x1b + (size_t)jj * 64 + g * 8);
    bf16x8 a0 = __builtin_bit_cast(bf16x8, pi[0]);
    bf16x8 a1 = __builtin_bit_cast(bf16x8, pi[2]);  // +32 elems = +2 uint32x4
    bf16x8 a2 = __builtin_bit_cast(bf16x8, pj[0]);
    bf16x8 a3 = __builtin_bit_cast(bf16x8, pj[2]);
#pragma unroll
    for (int ct = 0; ct < 4; ++ct) {
      f32x4 acc = mfma16(a0, wn1f[0][ct], z);
      acc = mfma16(a1, wn1f[1][ct], acc);
      acc = mfma16(a2, wn1f[2][ct], acc);
      acc = mfma16(a3, wn1f[3][ct], acc);
#pragma unroll
      for (int r = 0; r < 4; ++r)
        lds[(wrow + r) * LSTR + ct * 16 + wcol] = silu_f(acc[r] + bn1[ct]);
    }
    LDS_FENCE();
    bf16x8 t0 = pack8(lds + l15 * LSTR + g * 8);
    bf16x8 t1 = pack8(lds + l15 * LSTR + 32 + g * 8);
    f32x4 acc2[4];
#pragma unroll
    for (int ct = 0; ct < 4; ++ct) {
      acc2[ct] = mfma16(t0, wn2f[0][ct], z);
      acc2[ct] = mfma16(t1, wn2f[1][ct], acc2[ct]);
    }
#pragma unroll
    for (int r = 0; r < 4; ++r) {
      int ge = s * 16 + wrow + r;
      int ni = idx_i[ge];
#pragma unroll
      for (int ct = 0; ct < 4; ++ct) {
        float f = silu_f(acc2[ct][r] + bn2[ct]);
        float m = lcao[(size_t)ge * 64 + ct * 16 + l15] * f;
        atomicAdd(&nodeagg[(size_t)ni * 64 + ct * 16 + l15], m);
      }
    }
  }
}

// K7: out = x + nodeagg @ w_out
__global__ __launch_bounds__(256) void k_out(
    const float* __restrict__ x, const float* __restrict__ nodeagg,
    const float* __restrict__ w_out, float* __restrict__ out) {
  int lane = threadIdx.x & 63;
  int wid = (blockIdx.x * 256 + (int)threadIdx.x) >> 6;
  int nw = (gridDim.x * 256) >> 6;
  float wo0[64], wo1[64];
#pragma unroll
  for (int k = 0; k < 64; ++k) wo0[k] = w_out[k * H_DIM + lane];
#pragma unroll
  for (int k = 0; k < 64; ++k) wo1[k] = w_out[k * H_DIM + 64 + lane];
  for (int n = wid; n < N_NODES; n += nw) {
    float v = nodeagg[(size_t)n * 64 + lane];
    float a0 = 0.f, a1 = 0.f;
#pragma unroll
    for (int k = 0; k < 64; ++k) {
      float a = rl(v, k);
      a0 = fmaf(a, wo0[k], a0);
      a1 = fmaf(a, wo1[k], a1);
    }
    out[(size_t)n * H_DIM + lane] = x[(size_t)n * H_DIM + lane] + a0;
    out[(size_t)n * H_DIM + 64 + lane] = x[(size_t)n * H_DIM + 64 + lane] + a1;
  }
}

extern "C" void kernel_launch(void* const* d_in, const int* in_sizes, int n_in,
                              void* d_out, int out_size, void* d_ws, size_t ws_size,
                              hipStream_t stream) {
  const float* x         = (const float*)d_in[0];
  const float* cji       = (const float*)d_in[1];
  const float* cutoff_w  = (const float*)d_in[2];
  const float* rb        = (const float*)d_in[3];
  const float* shb       = (const float*)d_in[4];
  const int*   idx_i     = (const int*)d_in[5];
  const int*   idx_j     = (const int*)d_in[6];
  const int*   tri_idx_k = (const int*)d_in[7];
  const int*   e_kj      = (const int*)d_in[8];
  const int*   e_ji      = (const int*)d_in[9];
  const float* w_node    = (const float*)d_in[10];
  const float* b_node    = (const float*)d_in[11];
  const float* w_c1      = (const float*)d_in[12];
  const float* w_c2      = (const float*)d_in[13];
  const float* w_t1      = (const float*)d_in[14];
  const float* b_t1      = (const float*)d_in[15];
  const float* w_t2      = (const float*)d_in[16];
  const float* b_t2      = (const float*)d_in[17];
  const float* w_basis   = (const float*)d_in[18];
  const float* w_n1      = (const float*)d_in[19];
  const float* b_n1      = (const float*)d_in[20];
  const float* w_n2      = (const float*)d_in[21];
  const float* b_n2      = (const float*)d_in[22];
  const float* w_out     = (const float*)d_in[23];
  float* out = (float*)d_out;

  char* ws = (char*)d_ws;
  ushort* x1b    = (ushort*)(ws + 0);            //  1,280,000 B
  ushort* sigxkb = (ushort*)(ws + 1280000);      //  1,280,000 B
  ushort* cji2   = (ushort*)(ws + 2560000);      // 115,200,000 B
  float*  aggbuf = (float*)(ws + 117760000);     //  25,600,000 B
  float*  lcao   = (float*)(ws + 143360000);     //  25,600,000 B
  float*  nodeagg= (float*)(ws + 168960000);     //   2,560,000 B

  hipMemsetAsync(aggbuf, 0, (size_t)6400000 * sizeof(float), stream);
  hipMemsetAsync(nodeagg, 0, (size_t)640000 * sizeof(float), stream);

  k_node_mlp<<<N_NODES, 128, 0, stream>>>(x, w_node, b_node, x1b, sigxkb);
  k_cji_mlp_mfma<<<2048, 256, 0, stream>>>(cji, w_c1, w_c2, cji2);
  k_triplet<<<2048, 256, 0, stream>>>(cji2, rb, cutoff_w, shb, tri_idx_k, e_kj,
                                      e_ji, sigxkb, aggbuf);
  k_tbw_lcao<<<1024, 256, 0, stream>>>(aggbuf, w_t1, b_t1, w_t2, b_t2, cji2,
                                       rb, cutoff_w, w_basis, lcao);
  k_msg_mfma<<<1024, 256, 0, stream>>>(x1b, idx_i, idx_j, w_n1, b_n1, w_n2,
                                       b_n2, lcao, nodeagg);
  k_out<<<256, 256, 0, stream>>>(x, nodeagg, w_out, out);
}